// Round 1
// baseline (3879.359 us; speedup 1.0000x reference)
//
#include <hip/hip_runtime.h>

#define D 128

__device__ __forceinline__ unsigned fenc(float f) {
    unsigned u = __float_as_uint(f);
    return (u & 0x80000000u) ? ~u : (u | 0x80000000u);
}
__device__ __forceinline__ float fdec(unsigned u) {
    return (u & 0x80000000u) ? __uint_as_float(u ^ 0x80000000u) : __uint_as_float(~u);
}

// h = x @ W ; as_[i] = h[i]·a_src ; ad_[i] = h[i]·a_dst
__global__ void gemm_gat(const float* __restrict__ x, const float* __restrict__ W,
                         const float* __restrict__ a_src, const float* __restrict__ a_dst,
                         float* __restrict__ h, float* __restrict__ as_, float* __restrict__ ad_,
                         int n) {
    int row = blockIdx.x * blockDim.x + threadIdx.x;
    if (row >= n) return;
    float acc[D];
#pragma unroll
    for (int d = 0; d < D; ++d) acc[d] = 0.f;
    const float* xr = x + (size_t)row * D;
    for (int k = 0; k < D; k += 4) {
        float4 xv = *(const float4*)(xr + k);
#pragma unroll
        for (int kk = 0; kk < 4; ++kk) {
            float xk = (&xv.x)[kk];
            const float* wr = W + (size_t)(k + kk) * D;  // wave-uniform address -> s_load
#pragma unroll
            for (int d = 0; d < D; ++d) acc[d] = fmaf(xk, wr[d], acc[d]);
        }
    }
    float s1 = 0.f, s2 = 0.f;
    float* hr = h + (size_t)row * D;
#pragma unroll
    for (int d = 0; d < D; ++d) {
        hr[d] = acc[d];
        s1 = fmaf(acc[d], a_src[d], s1);
        s2 = fmaf(acc[d], a_dst[d], s2);
    }
    as_[row] = s1;
    ad_[row] = s2;
}

__device__ __forceinline__ void edge_decode(const int* __restrict__ ad_idx, int E, int n, int e,
                                            int& src, int& dst) {
    if (e < E) { src = ad_idx[e]; dst = ad_idx[E + e]; }
    else       { src = dst = e - E; }
}

__global__ void edge_max(const int* __restrict__ ad_idx, int E, int n,
                         const float* __restrict__ as_, const float* __restrict__ ad_,
                         unsigned* __restrict__ emax_u) {
    int e = blockIdx.x * blockDim.x + threadIdx.x;
    int Et = E + n;
    if (e >= Et) return;
    int src, dst;
    edge_decode(ad_idx, E, n, e, src, dst);
    float v = as_[src] + ad_[dst];
    v = v >= 0.f ? v : 0.2f * v;
    atomicMax(&emax_u[dst], fenc(v));
}

__global__ void edge_ee(const int* __restrict__ ad_idx, int E, int n,
                        const float* __restrict__ as_, const float* __restrict__ ad_,
                        const unsigned* __restrict__ emax_u,
                        float* __restrict__ ee, float* __restrict__ denom) {
    int e = blockIdx.x * blockDim.x + threadIdx.x;
    int Et = E + n;
    if (e >= Et) return;
    int src, dst;
    edge_decode(ad_idx, E, n, e, src, dst);
    float v = as_[src] + ad_[dst];
    v = v >= 0.f ? v : 0.2f * v;
    float m = fdec(emax_u[dst]);
    float u = expf(v - m);
    ee[e] = u;
    atomicAdd(&denom[dst], u);
}

// one thread handles (edge, 4 dims)
__global__ void edge_acc(const int* __restrict__ ad_idx, int E, int n,
                         const float* __restrict__ ee, const float* __restrict__ denom,
                         const float* __restrict__ h, float* __restrict__ out) {
    long long tid = (long long)blockIdx.x * blockDim.x + threadIdx.x;
    int Et = E + n;
    int e = (int)(tid >> 5);
    int q = (int)(tid & 31);
    if (e >= Et) return;
    int src, dst;
    edge_decode(ad_idx, E, n, e, src, dst);
    float alpha = ee[e] / (denom[dst] + 1e-16f);
    const float4 hv = *(const float4*)(h + (size_t)src * D + q * 4);
    float* op = out + (size_t)dst * D + q * 4;
    atomicAdd(op + 0, hv.x * alpha);
    atomicAdd(op + 1, hv.y * alpha);
    atomicAdd(op + 2, hv.z * alpha);
    atomicAdd(op + 3, hv.w * alpha);
}

__global__ void relu_bias(float* __restrict__ xio, const float* __restrict__ b, int n) {
    int t = blockIdx.x * blockDim.x + threadIdx.x;
    if (t >= n * D) return;
    int d = t & (D - 1);
    float v = xio[t] + b[d];
    xio[t] = v > 0.f ? v : 0.f;
}

__global__ void head_li(const float* __restrict__ x, const float* __restrict__ w_lin,
                        const float* __restrict__ b_lin, const int* __restrict__ resmask,
                        float* __restrict__ pr, unsigned* __restrict__ limax_u, int n) {
    int i = blockIdx.x * blockDim.x + threadIdx.x;
    unsigned enc = 0u;
    if (i < n) {
        const float* xr = x + (size_t)i * D;
        float s = 0.f;
#pragma unroll
        for (int d = 0; d < D; d += 4) {
            float4 xv = *(const float4*)(xr + d);
            float4 wv = *(const float4*)(w_lin + d);
            s = fmaf(xv.x, wv.x, s);
            s = fmaf(xv.y, wv.y, s);
            s = fmaf(xv.z, wv.z, s);
            s = fmaf(xv.w, wv.w, s);
        }
        s += b_lin[0];
        if (resmask[i] == 0) s = -1000000000.0f;
        pr[i] = s;
        enc = fenc(s);
    }
    unsigned t = enc;
    for (int off = 32; off; off >>= 1) {
        unsigned o = __shfl_down(t, off);
        t = t > o ? t : o;
    }
    if ((threadIdx.x & 63) == 0) atomicMax(limax_u, t);
}

__global__ void head_exp(float* __restrict__ pr, const unsigned* __restrict__ limax_u,
                         float* __restrict__ sumexp, int n) {
    int i = blockIdx.x * blockDim.x + threadIdx.x;
    float m = fdec(*limax_u);
    float u = 0.f;
    if (i < n) {
        u = expf(pr[i] - m);
        pr[i] = u;
    }
    float t = u;
    for (int off = 32; off; off >>= 1) t += __shfl_down(t, off);
    if ((threadIdx.x & 63) == 0) atomicAdd(sumexp, t);
}

__global__ void head_final(float* __restrict__ pr, const float* __restrict__ sumexp,
                           const float* __restrict__ res, const int* __restrict__ resmask,
                           float* __restrict__ loss_out, float* __restrict__ maskf, int n) {
    int i = blockIdx.x * blockDim.x + threadIdx.x;
    float lt = 0.f;
    if (i < n) {
        float p = pr[i] / (*sumexp);
        pr[i] = p;
        float pc = fminf(fmaxf(p, 1e-10f), 1.0f);
        lt = -logf(pc) * res[i];
        maskf[i] = (float)resmask[i];
    }
    float t = lt;
    for (int off = 32; off; off >>= 1) t += __shfl_down(t, off);
    if ((threadIdx.x & 63) == 0) atomicAdd(loss_out, t);
}

__global__ void emit_x(const float* __restrict__ x2, float* __restrict__ xout,
                       float* __restrict__ sout, const int* __restrict__ num_res, int n) {
    int t = blockIdx.x * blockDim.x + threadIdx.x;
    if (t >= n * D) return;
    float v = x2[t];
    xout[t] = v;
    int row = t >> 7;
    if (row < num_res[0]) sout[t] = v;
}

extern "C" void kernel_launch(void* const* d_in, const int* in_sizes, int n_in,
                              void* d_out, int out_size, void* d_ws, size_t ws_size,
                              hipStream_t stream) {
    const float* input_node = (const float*)d_in[0];
    const int*   inputad    = (const int*)d_in[1];
    const float* res        = (const float*)d_in[2];
    const int*   resmask    = (const int*)d_in[3];
    const int*   num_res    = (const int*)d_in[4];
    const float* W1     = (const float*)d_in[5];
    const float* a_src1 = (const float*)d_in[6];
    const float* a_dst1 = (const float*)d_in[7];
    const float* b1     = (const float*)d_in[8];
    const float* W2     = (const float*)d_in[9];
    const float* a_src2 = (const float*)d_in[10];
    const float* a_dst2 = (const float*)d_in[11];
    const float* b2     = (const float*)d_in[12];
    const float* w_lin  = (const float*)d_in[13];
    const float* b_lin  = (const float*)d_in[14];

    int n = in_sizes[0] / D;
    int E = in_sizes[1] / 2;
    int Et = E + n;

    // workspace carve (all 16B aligned)
    char* w = (char*)d_ws;
    float* h    = (float*)w; w += (size_t)n * D * 4;
    float* xbuf = (float*)w; w += (size_t)n * D * 4;   // x1, then out2/x2
    float* as_  = (float*)w; w += (size_t)n * 4;
    float* ad_  = (float*)w; w += (size_t)n * 4;
    unsigned* emax_u = (unsigned*)w; w += (size_t)n * 4;
    float* denom = (float*)w; w += (size_t)n * 4;
    float* ee   = (float*)w; w += (size_t)Et * 4;
    unsigned* limax_u = (unsigned*)w; w += 16;
    float* sumexp = (float*)w; w += 16;

    // d_out carve (element offsets are odd -> scalar stores only)
    float* out0  = (float*)d_out;            // loss (1)
    float* prob  = out0 + 1;                 // N
    float* xout  = prob + n;                 // N*D
    float* maskf = xout + (size_t)n * D;     // N
    float* sout  = maskf + n;                // K*D

    dim3 blk(256);
    auto cdiv = [](long long a, long long b) { return (unsigned)((a + b - 1) / b); };

    // ---- Layer 1 ----
    gemm_gat<<<cdiv(n, 256), blk, 0, stream>>>(input_node, W1, a_src1, a_dst1, h, as_, ad_, n);
    hipMemsetAsync(emax_u, 0, (size_t)n * 4, stream);
    hipMemsetAsync(denom, 0, (size_t)n * 4, stream);
    hipMemsetAsync(xbuf, 0, (size_t)n * D * 4, stream);
    edge_max<<<cdiv(Et, 256), blk, 0, stream>>>(inputad, E, n, as_, ad_, emax_u);
    edge_ee<<<cdiv(Et, 256), blk, 0, stream>>>(inputad, E, n, as_, ad_, emax_u, ee, denom);
    edge_acc<<<cdiv((long long)Et * 32, 256), blk, 0, stream>>>(inputad, E, n, ee, denom, h, xbuf);
    relu_bias<<<cdiv((long long)n * D, 256), blk, 0, stream>>>(xbuf, b1, n);

    // ---- Layer 2 ----
    gemm_gat<<<cdiv(n, 256), blk, 0, stream>>>(xbuf, W2, a_src2, a_dst2, h, as_, ad_, n);
    hipMemsetAsync(emax_u, 0, (size_t)n * 4, stream);
    hipMemsetAsync(denom, 0, (size_t)n * 4, stream);
    hipMemsetAsync(xbuf, 0, (size_t)n * D * 4, stream);  // gemm2 already consumed xbuf
    edge_max<<<cdiv(Et, 256), blk, 0, stream>>>(inputad, E, n, as_, ad_, emax_u);
    edge_ee<<<cdiv(Et, 256), blk, 0, stream>>>(inputad, E, n, as_, ad_, emax_u, ee, denom);
    edge_acc<<<cdiv((long long)Et * 32, 256), blk, 0, stream>>>(inputad, E, n, ee, denom, h, xbuf);
    relu_bias<<<cdiv((long long)n * D, 256), blk, 0, stream>>>(xbuf, b2, n);

    // ---- Head ----
    hipMemsetAsync(limax_u, 0, 4, stream);
    hipMemsetAsync(sumexp, 0, 4, stream);
    hipMemsetAsync(out0, 0, 4, stream);
    head_li<<<cdiv(n, 256), blk, 0, stream>>>(xbuf, w_lin, b_lin, resmask, prob, limax_u, n);
    head_exp<<<cdiv(n, 256), blk, 0, stream>>>(prob, limax_u, sumexp, n);
    head_final<<<cdiv(n, 256), blk, 0, stream>>>(prob, sumexp, res, resmask, out0, maskf, n);
    emit_x<<<cdiv((long long)n * D, 256), blk, 0, stream>>>(xbuf, xout, sout, num_res, n);
}

// Round 2
// 1054.060 us; speedup vs baseline: 3.6804x; 3.6804x over previous
//
#include <hip/hip_runtime.h>

#define D 128
#define CACHE 8   // per-lane cached edges -> supports deg <= 512 (actual max ~45)

__device__ __forceinline__ unsigned fenc(float f) {
    unsigned u = __float_as_uint(f);
    return (u & 0x80000000u) ? ~u : (u | 0x80000000u);
}
__device__ __forceinline__ float fdec(unsigned u) {
    return (u & 0x80000000u) ? __uint_as_float(u ^ 0x80000000u) : __uint_as_float(~u);
}

// h = x @ W ; as_[i] = h[i]·a_src ; ad_[i] = h[i]·a_dst
__global__ void gemm_gat(const float* __restrict__ x, const float* __restrict__ W,
                         const float* __restrict__ a_src, const float* __restrict__ a_dst,
                         float* __restrict__ h, float* __restrict__ as_, float* __restrict__ ad_,
                         int n) {
    int row = blockIdx.x * blockDim.x + threadIdx.x;
    if (row >= n) return;
    float acc[D];
#pragma unroll
    for (int d = 0; d < D; ++d) acc[d] = 0.f;
    const float* xr = x + (size_t)row * D;
    for (int k = 0; k < D; k += 4) {
        float4 xv = *(const float4*)(xr + k);
#pragma unroll
        for (int kk = 0; kk < 4; ++kk) {
            float xk = (&xv.x)[kk];
            const float* wr = W + (size_t)(k + kk) * D;  // wave-uniform -> scalar loads
#pragma unroll
            for (int d = 0; d < D; ++d) acc[d] = fmaf(xk, wr[d], acc[d]);
        }
    }
    float s1 = 0.f, s2 = 0.f;
    float* hr = h + (size_t)row * D;
#pragma unroll
    for (int d = 0; d < D; ++d) {
        hr[d] = acc[d];
        s1 = fmaf(acc[d], a_src[d], s1);
        s2 = fmaf(acc[d], a_dst[d], s2);
    }
    as_[row] = s1;
    ad_[row] = s2;
}

// ---------------- CSR build (graph is layer-invariant) ----------------

__global__ void deg_hist(const int* __restrict__ ad_idx, int E, int n, int* __restrict__ cnt) {
    int e = blockIdx.x * blockDim.x + threadIdx.x;
    if (e >= E + n) return;
    int dst = (e < E) ? ad_idx[E + e] : (e - E);
    atomicAdd(&cnt[dst], 1);
}

__global__ void scan1(const int* __restrict__ cnt, int* __restrict__ start,
                      int* __restrict__ bsum, int n) {
    __shared__ int lds[256];
    int t = threadIdx.x;
    int i = blockIdx.x * 256 + t;
    int v = (i < n) ? cnt[i] : 0;
    lds[t] = v;
    __syncthreads();
    for (int off = 1; off < 256; off <<= 1) {
        int o = (t >= off) ? lds[t - off] : 0;
        __syncthreads();
        lds[t] += o;
        __syncthreads();
    }
    int incl = lds[t];
    if (i < n) start[i] = incl - v;         // exclusive within block
    if (t == 255) bsum[blockIdx.x] = incl;  // block total
}

__global__ void scan2(int* __restrict__ bsum, int nb) {
    __shared__ int lds[256];
    int t = threadIdx.x;
    int v = (t < nb) ? bsum[t] : 0;
    lds[t] = v;
    __syncthreads();
    for (int off = 1; off < 256; off <<= 1) {
        int o = (t >= off) ? lds[t - off] : 0;
        __syncthreads();
        lds[t] += o;
        __syncthreads();
    }
    if (t < nb) bsum[t] = lds[t] - v;       // exclusive block offsets
}

__global__ void scan3(int* __restrict__ start, const int* __restrict__ bsum, int n) {
    int i = blockIdx.x * blockDim.x + threadIdx.x;
    if (i < n) start[i] += bsum[blockIdx.x];
}

__global__ void csr_scatter(const int* __restrict__ ad_idx, int E, int n,
                            const int* __restrict__ start, int* __restrict__ cursor,
                            int* __restrict__ csr_src) {
    int e = blockIdx.x * blockDim.x + threadIdx.x;
    if (e >= E + n) return;
    int src, dst;
    if (e < E) { src = ad_idx[e]; dst = ad_idx[E + e]; }
    else       { src = dst = e - E; }
    int r = atomicAdd(&cursor[dst], 1);
    csr_src[start[dst] + r] = src;
}

// ---------------- fused per-node edge softmax + gather + bias + relu ----------------
// one wave per dst node; lanes cover the 128 dims (float2 each)
__global__ void gat_aggregate(const int* __restrict__ csr_src, const int* __restrict__ start,
                              const int* __restrict__ deg, const float* __restrict__ as_,
                              const float* __restrict__ ad_, const float* __restrict__ h,
                              const float* __restrict__ bias, float* __restrict__ out, int n) {
    int wid = threadIdx.x >> 6;
    int lane = threadIdx.x & 63;
    int node = blockIdx.x * (blockDim.x >> 6) + wid;
    if (node >= n) return;
    int s0 = start[node];
    int dg = deg[node];
    float adv = ad_[node];

    float vreg[CACHE];
    int   sreg[CACHE];
    float m = -3.4e38f;
#pragma unroll
    for (int c = 0; c < CACHE; ++c) {
        int j = c * 64 + lane;
        bool ok = j < dg;
        int s = ok ? csr_src[s0 + j] : 0;
        sreg[c] = s;
        float v = -3.4e38f;
        if (ok) {
            v = as_[s] + adv;
            v = v >= 0.f ? v : 0.2f * v;
        }
        vreg[c] = v;
        m = fmaxf(m, v);
    }
    for (int off = 32; off; off >>= 1) m = fmaxf(m, __shfl_xor(m, off));

    float dsum = 0.f;
#pragma unroll
    for (int c = 0; c < CACHE; ++c) {
        int j = c * 64 + lane;
        float e = (j < dg) ? __expf(vreg[c] - m) : 0.f;
        vreg[c] = e;
        dsum += e;
    }
    for (int off = 32; off; off >>= 1) dsum += __shfl_xor(dsum, off);
    float inv = 1.f / (dsum + 1e-16f);

    float acc0 = 0.f, acc1 = 0.f;
#pragma unroll
    for (int c = 0; c < CACHE; ++c) {
        if (c * 64 < dg) {
            int mc = min(64, dg - c * 64);
            for (int l = 0; l < mc; ++l) {
                float a   = __shfl(vreg[c], l) * inv;
                int  srcj = __shfl(sreg[c], l);
                float2 hv = *(const float2*)(h + (size_t)srcj * D + lane * 2);
                acc0 = fmaf(a, hv.x, acc0);
                acc1 = fmaf(a, hv.y, acc1);
            }
        }
    }
    float2 bv = *(const float2*)(bias + lane * 2);
    float o0 = acc0 + bv.x, o1 = acc1 + bv.y;
    o0 = o0 > 0.f ? o0 : 0.f;
    o1 = o1 > 0.f ? o1 : 0.f;
    *(float2*)(out + (size_t)node * D + lane * 2) = make_float2(o0, o1);
}

// ---------------- head ----------------

__global__ void head_li(const float* __restrict__ x, const float* __restrict__ w_lin,
                        const float* __restrict__ b_lin, const int* __restrict__ resmask,
                        float* __restrict__ pr, unsigned* __restrict__ limax_u, int n) {
    int i = blockIdx.x * blockDim.x + threadIdx.x;
    unsigned enc = 0u;
    if (i < n) {
        const float* xr = x + (size_t)i * D;
        float s = 0.f;
#pragma unroll
        for (int d = 0; d < D; d += 4) {
            float4 xv = *(const float4*)(xr + d);
            float4 wv = *(const float4*)(w_lin + d);
            s = fmaf(xv.x, wv.x, s);
            s = fmaf(xv.y, wv.y, s);
            s = fmaf(xv.z, wv.z, s);
            s = fmaf(xv.w, wv.w, s);
        }
        s += b_lin[0];
        if (resmask[i] == 0) s = -1000000000.0f;
        pr[i] = s;
        enc = fenc(s);
    }
    unsigned t = enc;
    for (int off = 32; off; off >>= 1) {
        unsigned o = __shfl_down(t, off);
        t = t > o ? t : o;
    }
    if ((threadIdx.x & 63) == 0) atomicMax(limax_u, t);
}

__global__ void head_exp(float* __restrict__ pr, const unsigned* __restrict__ limax_u,
                         float* __restrict__ sumexp, int n) {
    int i = blockIdx.x * blockDim.x + threadIdx.x;
    float m = fdec(*limax_u);
    float u = 0.f;
    if (i < n) {
        u = expf(pr[i] - m);
        pr[i] = u;
    }
    float t = u;
    for (int off = 32; off; off >>= 1) t += __shfl_down(t, off);
    if ((threadIdx.x & 63) == 0) atomicAdd(sumexp, t);
}

__global__ void head_final(float* __restrict__ pr, const float* __restrict__ sumexp,
                           const float* __restrict__ res, const int* __restrict__ resmask,
                           float* __restrict__ loss_out, float* __restrict__ maskf, int n) {
    int i = blockIdx.x * blockDim.x + threadIdx.x;
    float lt = 0.f;
    if (i < n) {
        float p = pr[i] / (*sumexp);
        pr[i] = p;
        float pc = fminf(fmaxf(p, 1e-10f), 1.0f);
        lt = -logf(pc) * res[i];
        maskf[i] = (float)resmask[i];
    }
    float t = lt;
    for (int off = 32; off; off >>= 1) t += __shfl_down(t, off);
    if ((threadIdx.x & 63) == 0) atomicAdd(loss_out, t);
}

__global__ void emit_x(const float* __restrict__ x2, float* __restrict__ xout,
                       float* __restrict__ sout, const int* __restrict__ num_res, int n) {
    int t = blockIdx.x * blockDim.x + threadIdx.x;
    if (t >= n * D) return;
    float v = x2[t];
    xout[t] = v;
    int row = t >> 7;
    if (row < num_res[0]) sout[t] = v;
}

extern "C" void kernel_launch(void* const* d_in, const int* in_sizes, int n_in,
                              void* d_out, int out_size, void* d_ws, size_t ws_size,
                              hipStream_t stream) {
    const float* input_node = (const float*)d_in[0];
    const int*   inputad    = (const int*)d_in[1];
    const float* res        = (const float*)d_in[2];
    const int*   resmask    = (const int*)d_in[3];
    const int*   num_res    = (const int*)d_in[4];
    const float* W1     = (const float*)d_in[5];
    const float* a_src1 = (const float*)d_in[6];
    const float* a_dst1 = (const float*)d_in[7];
    const float* b1     = (const float*)d_in[8];
    const float* W2     = (const float*)d_in[9];
    const float* a_src2 = (const float*)d_in[10];
    const float* a_dst2 = (const float*)d_in[11];
    const float* b2     = (const float*)d_in[12];
    const float* w_lin  = (const float*)d_in[13];
    const float* b_lin  = (const float*)d_in[14];

    int n = in_sizes[0] / D;
    int E = in_sizes[1] / 2;
    int Et = E + n;

    // workspace carve (16B aligned pieces)
    char* w = (char*)d_ws;
    float* h     = (float*)w; w += (size_t)n * D * 4;
    float* xbuf  = (float*)w; w += (size_t)n * D * 4;
    float* as_   = (float*)w; w += (size_t)n * 4;
    float* ad_   = (float*)w; w += (size_t)n * 4;
    int*   deg   = (int*)w;   w += (size_t)n * 4;
    int*   startv= (int*)w;   w += (size_t)n * 4;
    int*   cursor= (int*)w;   w += (size_t)n * 4;
    int*   csr_src=(int*)w;   w += (size_t)Et * 4;
    int*   bsum  = (int*)w;   w += 1024;
    unsigned* limax_u = (unsigned*)w; w += 16;
    float* sumexp = (float*)w; w += 16;

    // d_out carve
    float* out0  = (float*)d_out;            // loss (1)
    float* prob  = out0 + 1;                 // N
    float* xout  = prob + n;                 // N*D
    float* maskf = xout + (size_t)n * D;     // N
    float* sout  = maskf + n;                // K*D

    dim3 blk(256);
    auto cdiv = [](long long a, long long b) { return (unsigned)((a + b - 1) / b); };
    unsigned nb = cdiv(n, 256);

    // ---- CSR build (once; graph shared by both layers) ----
    hipMemsetAsync(deg, 0, (size_t)n * 4, stream);
    deg_hist<<<cdiv(Et, 256), blk, 0, stream>>>(inputad, E, n, deg);
    scan1<<<nb, blk, 0, stream>>>(deg, startv, bsum, n);
    scan2<<<1, blk, 0, stream>>>(bsum, (int)nb);
    scan3<<<nb, blk, 0, stream>>>(startv, bsum, n);
    hipMemsetAsync(cursor, 0, (size_t)n * 4, stream);
    csr_scatter<<<cdiv(Et, 256), blk, 0, stream>>>(inputad, E, n, startv, cursor, csr_src);

    unsigned agg_grid = cdiv(n, 4);  // 4 waves/block, 1 node/wave

    // ---- Layer 1 ----
    gemm_gat<<<cdiv(n, 256), blk, 0, stream>>>(input_node, W1, a_src1, a_dst1, h, as_, ad_, n);
    gat_aggregate<<<agg_grid, blk, 0, stream>>>(csr_src, startv, deg, as_, ad_, h, b1, xbuf, n);

    // ---- Layer 2 ----
    gemm_gat<<<cdiv(n, 256), blk, 0, stream>>>(xbuf, W2, a_src2, a_dst2, h, as_, ad_, n);
    gat_aggregate<<<agg_grid, blk, 0, stream>>>(csr_src, startv, deg, as_, ad_, h, b2, xbuf, n);

    // ---- Head ----
    hipMemsetAsync(limax_u, 0, 4, stream);
    hipMemsetAsync(sumexp, 0, 4, stream);
    hipMemsetAsync(out0, 0, 4, stream);
    head_li<<<cdiv(n, 256), blk, 0, stream>>>(xbuf, w_lin, b_lin, resmask, prob, limax_u, n);
    head_exp<<<cdiv(n, 256), blk, 0, stream>>>(prob, limax_u, sumexp, n);
    head_final<<<cdiv(n, 256), blk, 0, stream>>>(prob, sumexp, res, resmask, out0, maskf, n);
    emit_x<<<cdiv((long long)n * D, 256), blk, 0, stream>>>(xbuf, xout, sout, num_res, n);
}

// Round 3
// 374.792 us; speedup vs baseline: 10.3507x; 2.8124x over previous
//
#include <hip/hip_runtime.h>

#define D 128
#define BM 64
#define BK 32
#define CACHE 8   // per-lane cached edges -> supports deg <= 512 (actual max ~45)

__device__ __forceinline__ unsigned fenc(float f) {
    unsigned u = __float_as_uint(f);
    return (u & 0x80000000u) ? ~u : (u | 0x80000000u);
}
__device__ __forceinline__ float fdec(unsigned u) {
    return (u & 0x80000000u) ? __uint_as_float(u ^ 0x80000000u) : __uint_as_float(~u);
}

// ---------------- tiled f32 GEMM: h = x @ W  (K = N = 128) ----------------
__global__ __launch_bounds__(256) void gemm_tile(const float* __restrict__ x,
                                                 const float* __restrict__ W,
                                                 float* __restrict__ h, int n) {
    __shared__ float xs[BM][BK + 4];   // +4 pad: rows stay 16B-aligned, banks spread
    __shared__ float ws[BK][D];
    int tid = threadIdx.x;
    int br = blockIdx.x * BM;
    int tx = tid & 15;    // col group: cols tx*8 .. tx*8+7
    int ty = tid >> 4;    // row group: rows ty*4 .. ty*4+3
    float acc[4][8];
#pragma unroll
    for (int r = 0; r < 4; ++r)
#pragma unroll
        for (int c = 0; c < 8; ++c) acc[r][c] = 0.f;

    for (int kt = 0; kt < D; kt += BK) {
        // stage x tile: 64x32 floats = 512 float4, 2 per thread
#pragma unroll
        for (int it = 0; it < 2; ++it) {
            int idx = it * 256 + tid;
            int r = idx >> 3;
            int c4 = idx & 7;
            int gr = br + r;
            float4 v = make_float4(0.f, 0.f, 0.f, 0.f);
            if (gr < n) v = *(const float4*)(x + (size_t)gr * D + kt + c4 * 4);
            *(float4*)(&xs[r][c4 * 4]) = v;
        }
        // stage W tile: 32x128 floats = 1024 float4, 4 per thread
#pragma unroll
        for (int it = 0; it < 4; ++it) {
            int idx = it * 256 + tid;
            int r = idx >> 5;
            int c4 = idx & 31;
            *(float4*)(&ws[r][c4 * 4]) = *(const float4*)(W + (size_t)(kt + r) * D + c4 * 4);
        }
        __syncthreads();
#pragma unroll
        for (int k = 0; k < BK; ++k) {
            float xv[4];
#pragma unroll
            for (int r = 0; r < 4; ++r) xv[r] = xs[ty * 4 + r][k];
            float4 w0 = *(const float4*)(&ws[k][tx * 8]);
            float4 w1 = *(const float4*)(&ws[k][tx * 8 + 4]);
#pragma unroll
            for (int r = 0; r < 4; ++r) {
                acc[r][0] = fmaf(xv[r], w0.x, acc[r][0]);
                acc[r][1] = fmaf(xv[r], w0.y, acc[r][1]);
                acc[r][2] = fmaf(xv[r], w0.z, acc[r][2]);
                acc[r][3] = fmaf(xv[r], w0.w, acc[r][3]);
                acc[r][4] = fmaf(xv[r], w1.x, acc[r][4]);
                acc[r][5] = fmaf(xv[r], w1.y, acc[r][5]);
                acc[r][6] = fmaf(xv[r], w1.z, acc[r][6]);
                acc[r][7] = fmaf(xv[r], w1.w, acc[r][7]);
            }
        }
        __syncthreads();
    }
#pragma unroll
    for (int r = 0; r < 4; ++r) {
        int gr = br + ty * 4 + r;
        if (gr < n) {
            *(float4*)(h + (size_t)gr * D + tx * 8) =
                make_float4(acc[r][0], acc[r][1], acc[r][2], acc[r][3]);
            *(float4*)(h + (size_t)gr * D + tx * 8 + 4) =
                make_float4(acc[r][4], acc[r][5], acc[r][6], acc[r][7]);
        }
    }
}

// as_[i] = h[i]·a_src ; ad_[i] = h[i]·a_dst  (one wave per row)
__global__ void dots(const float* __restrict__ h, const float* __restrict__ a_src,
                     const float* __restrict__ a_dst, float* __restrict__ as_,
                     float* __restrict__ ad_, int n) {
    int wid = threadIdx.x >> 6;
    int lane = threadIdx.x & 63;
    int row = blockIdx.x * (blockDim.x >> 6) + wid;
    if (row >= n) return;
    float2 hv = *(const float2*)(h + (size_t)row * D + lane * 2);
    float2 sv = *(const float2*)(a_src + lane * 2);
    float2 dv = *(const float2*)(a_dst + lane * 2);
    float v1 = fmaf(hv.x, sv.x, hv.y * sv.y);
    float v2 = fmaf(hv.x, dv.x, hv.y * dv.y);
    for (int off = 32; off; off >>= 1) {
        v1 += __shfl_xor(v1, off);
        v2 += __shfl_xor(v2, off);
    }
    if (lane == 0) { as_[row] = v1; ad_[row] = v2; }
}

// ---------------- CSR build (graph is layer-invariant) ----------------

__global__ void deg_hist(const int* __restrict__ ad_idx, int E, int n, int* __restrict__ cnt) {
    int e = blockIdx.x * blockDim.x + threadIdx.x;
    if (e >= E + n) return;
    int dst = (e < E) ? ad_idx[E + e] : (e - E);
    atomicAdd(&cnt[dst], 1);
}

__global__ void scan1(const int* __restrict__ cnt, int* __restrict__ start,
                      int* __restrict__ bsum, int n) {
    __shared__ int lds[256];
    int t = threadIdx.x;
    int i = blockIdx.x * 256 + t;
    int v = (i < n) ? cnt[i] : 0;
    lds[t] = v;
    __syncthreads();
    for (int off = 1; off < 256; off <<= 1) {
        int o = (t >= off) ? lds[t - off] : 0;
        __syncthreads();
        lds[t] += o;
        __syncthreads();
    }
    int incl = lds[t];
    if (i < n) start[i] = incl - v;
    if (t == 255) bsum[blockIdx.x] = incl;
}

__global__ void scan2(int* __restrict__ bsum, int nb) {
    __shared__ int lds[256];
    int t = threadIdx.x;
    int v = (t < nb) ? bsum[t] : 0;
    lds[t] = v;
    __syncthreads();
    for (int off = 1; off < 256; off <<= 1) {
        int o = (t >= off) ? lds[t - off] : 0;
        __syncthreads();
        lds[t] += o;
        __syncthreads();
    }
    if (t < nb) bsum[t] = lds[t] - v;
}

__global__ void scan3(int* __restrict__ start, const int* __restrict__ bsum, int n) {
    int i = blockIdx.x * blockDim.x + threadIdx.x;
    if (i < n) start[i] += bsum[blockIdx.x];
}

__global__ void csr_scatter(const int* __restrict__ ad_idx, int E, int n,
                            const int* __restrict__ start, int* __restrict__ cursor,
                            int* __restrict__ csr_src) {
    int e = blockIdx.x * blockDim.x + threadIdx.x;
    if (e >= E + n) return;
    int src, dst;
    if (e < E) { src = ad_idx[e]; dst = ad_idx[E + e]; }
    else       { src = dst = e - E; }
    int r = atomicAdd(&cursor[dst], 1);
    csr_src[start[dst] + r] = src;
}

// ---------------- fused per-node edge softmax + gather + bias + relu ----------------
__global__ void gat_aggregate(const int* __restrict__ csr_src, const int* __restrict__ start,
                              const int* __restrict__ deg, const float* __restrict__ as_,
                              const float* __restrict__ ad_, const float* __restrict__ h,
                              const float* __restrict__ bias, float* __restrict__ out, int n) {
    int wid = threadIdx.x >> 6;
    int lane = threadIdx.x & 63;
    int node = blockIdx.x * (blockDim.x >> 6) + wid;
    if (node >= n) return;
    int s0 = start[node];
    int dg = deg[node];
    float adv = ad_[node];

    float vreg[CACHE];
    int   sreg[CACHE];
    float m = -3.4e38f;
#pragma unroll
    for (int c = 0; c < CACHE; ++c) {
        int j = c * 64 + lane;
        bool ok = j < dg;
        int s = ok ? csr_src[s0 + j] : 0;
        sreg[c] = s;
        float v = -3.4e38f;
        if (ok) {
            v = as_[s] + adv;
            v = v >= 0.f ? v : 0.2f * v;
        }
        vreg[c] = v;
        m = fmaxf(m, v);
    }
    for (int off = 32; off; off >>= 1) m = fmaxf(m, __shfl_xor(m, off));

    float dsum = 0.f;
#pragma unroll
    for (int c = 0; c < CACHE; ++c) {
        int j = c * 64 + lane;
        float e = (j < dg) ? __expf(vreg[c] - m) : 0.f;
        vreg[c] = e;
        dsum += e;
    }
    for (int off = 32; off; off >>= 1) dsum += __shfl_xor(dsum, off);
    float inv = 1.f / (dsum + 1e-16f);

    float acc0 = 0.f, acc1 = 0.f;
#pragma unroll
    for (int c = 0; c < CACHE; ++c) {
        if (c * 64 < dg) {
            int mc = min(64, dg - c * 64);
            for (int l = 0; l < mc; ++l) {
                float a   = __shfl(vreg[c], l) * inv;
                int  srcj = __shfl(sreg[c], l);
                float2 hv = *(const float2*)(h + (size_t)srcj * D + lane * 2);
                acc0 = fmaf(a, hv.x, acc0);
                acc1 = fmaf(a, hv.y, acc1);
            }
        }
    }
    float2 bv = *(const float2*)(bias + lane * 2);
    float o0 = acc0 + bv.x, o1 = acc1 + bv.y;
    o0 = o0 > 0.f ? o0 : 0.f;
    o1 = o1 > 0.f ? o1 : 0.f;
    *(float2*)(out + (size_t)node * D + lane * 2) = make_float2(o0, o1);
}

// ---------------- head ----------------

__global__ void head_li(const float* __restrict__ x, const float* __restrict__ w_lin,
                        const float* __restrict__ b_lin, const int* __restrict__ resmask,
                        float* __restrict__ pr, unsigned* __restrict__ limax_u, int n) {
    int i = blockIdx.x * blockDim.x + threadIdx.x;
    unsigned enc = 0u;
    if (i < n) {
        const float* xr = x + (size_t)i * D;
        float s = 0.f;
#pragma unroll
        for (int d = 0; d < D; d += 4) {
            float4 xv = *(const float4*)(xr + d);
            float4 wv = *(const float4*)(w_lin + d);
            s = fmaf(xv.x, wv.x, s);
            s = fmaf(xv.y, wv.y, s);
            s = fmaf(xv.z, wv.z, s);
            s = fmaf(xv.w, wv.w, s);
        }
        s += b_lin[0];
        if (resmask[i] == 0) s = -1000000000.0f;
        pr[i] = s;
        enc = fenc(s);
    }
    unsigned t = enc;
    for (int off = 32; off; off >>= 1) {
        unsigned o = __shfl_down(t, off);
        t = t > o ? t : o;
    }
    if ((threadIdx.x & 63) == 0) atomicMax(limax_u, t);
}

__global__ void head_exp(float* __restrict__ pr, const unsigned* __restrict__ limax_u,
                         float* __restrict__ sumexp, int n) {
    int i = blockIdx.x * blockDim.x + threadIdx.x;
    float m = fdec(*limax_u);
    float u = 0.f;
    if (i < n) {
        u = expf(pr[i] - m);
        pr[i] = u;
    }
    float t = u;
    for (int off = 32; off; off >>= 1) t += __shfl_down(t, off);
    if ((threadIdx.x & 63) == 0) atomicAdd(sumexp, t);
}

__global__ void head_final(float* __restrict__ pr, const float* __restrict__ sumexp,
                           const float* __restrict__ res, const int* __restrict__ resmask,
                           float* __restrict__ loss_out, float* __restrict__ maskf, int n) {
    int i = blockIdx.x * blockDim.x + threadIdx.x;
    float lt = 0.f;
    if (i < n) {
        float p = pr[i] / (*sumexp);
        pr[i] = p;
        float pc = fminf(fmaxf(p, 1e-10f), 1.0f);
        lt = -logf(pc) * res[i];
        maskf[i] = (float)resmask[i];
    }
    float t = lt;
    for (int off = 32; off; off >>= 1) t += __shfl_down(t, off);
    if ((threadIdx.x & 63) == 0) atomicAdd(loss_out, t);
}

__global__ void emit_x(const float* __restrict__ x2, float* __restrict__ xout,
                       float* __restrict__ sout, const int* __restrict__ num_res, int n) {
    int t = blockIdx.x * blockDim.x + threadIdx.x;
    if (t >= n * D) return;
    float v = x2[t];
    xout[t] = v;
    int row = t >> 7;
    if (row < num_res[0]) sout[t] = v;
}

extern "C" void kernel_launch(void* const* d_in, const int* in_sizes, int n_in,
                              void* d_out, int out_size, void* d_ws, size_t ws_size,
                              hipStream_t stream) {
    const float* input_node = (const float*)d_in[0];
    const int*   inputad    = (const int*)d_in[1];
    const float* res        = (const float*)d_in[2];
    const int*   resmask    = (const int*)d_in[3];
    const int*   num_res    = (const int*)d_in[4];
    const float* W1     = (const float*)d_in[5];
    const float* a_src1 = (const float*)d_in[6];
    const float* a_dst1 = (const float*)d_in[7];
    const float* b1     = (const float*)d_in[8];
    const float* W2     = (const float*)d_in[9];
    const float* a_src2 = (const float*)d_in[10];
    const float* a_dst2 = (const float*)d_in[11];
    const float* b2     = (const float*)d_in[12];
    const float* w_lin  = (const float*)d_in[13];
    const float* b_lin  = (const float*)d_in[14];

    int n = in_sizes[0] / D;
    int E = in_sizes[1] / 2;
    int Et = E + n;

    // workspace carve (16B aligned pieces)
    char* w = (char*)d_ws;
    float* h     = (float*)w; w += (size_t)n * D * 4;
    float* xbuf  = (float*)w; w += (size_t)n * D * 4;
    float* as_   = (float*)w; w += (size_t)n * 4;
    float* ad_   = (float*)w; w += (size_t)n * 4;
    int*   deg   = (int*)w;   w += (size_t)n * 4;
    int*   startv= (int*)w;   w += (size_t)n * 4;
    int*   cursor= (int*)w;   w += (size_t)n * 4;
    int*   csr_src=(int*)w;   w += (size_t)Et * 4;
    int*   bsum  = (int*)w;   w += 1024;
    unsigned* limax_u = (unsigned*)w; w += 16;
    float* sumexp = (float*)w; w += 16;

    // d_out carve
    float* out0  = (float*)d_out;            // loss (1)
    float* prob  = out0 + 1;                 // N
    float* xout  = prob + n;                 // N*D
    float* maskf = xout + (size_t)n * D;     // N
    float* sout  = maskf + n;                // K*D

    dim3 blk(256);
    auto cdiv = [](long long a, long long b) { return (unsigned)((a + b - 1) / b); };
    unsigned nb = cdiv(n, 256);

    // ---- CSR build (once; graph shared by both layers) ----
    hipMemsetAsync(deg, 0, (size_t)n * 4, stream);
    deg_hist<<<cdiv(Et, 256), blk, 0, stream>>>(inputad, E, n, deg);
    scan1<<<nb, blk, 0, stream>>>(deg, startv, bsum, n);
    scan2<<<1, blk, 0, stream>>>(bsum, (int)nb);
    scan3<<<nb, blk, 0, stream>>>(startv, bsum, n);
    hipMemsetAsync(cursor, 0, (size_t)n * 4, stream);
    csr_scatter<<<cdiv(Et, 256), blk, 0, stream>>>(inputad, E, n, startv, cursor, csr_src);

    unsigned agg_grid = cdiv(n, 4);   // 4 waves/block, 1 node/wave
    unsigned gemm_grid = cdiv(n, BM);

    // ---- Layer 1 ----
    gemm_tile<<<gemm_grid, blk, 0, stream>>>(input_node, W1, h, n);
    dots<<<cdiv(n, 4), blk, 0, stream>>>(h, a_src1, a_dst1, as_, ad_, n);
    gat_aggregate<<<agg_grid, blk, 0, stream>>>(csr_src, startv, deg, as_, ad_, h, b1, xbuf, n);

    // ---- Layer 2 ----
    gemm_tile<<<gemm_grid, blk, 0, stream>>>(xbuf, W2, h, n);
    dots<<<cdiv(n, 4), blk, 0, stream>>>(h, a_src2, a_dst2, as_, ad_, n);
    gat_aggregate<<<agg_grid, blk, 0, stream>>>(csr_src, startv, deg, as_, ad_, h, b2, xbuf, n);

    // ---- Head ----
    hipMemsetAsync(limax_u, 0, 4, stream);
    hipMemsetAsync(sumexp, 0, 4, stream);
    hipMemsetAsync(out0, 0, 4, stream);
    head_li<<<cdiv(n, 256), blk, 0, stream>>>(xbuf, w_lin, b_lin, resmask, prob, limax_u, n);
    head_exp<<<cdiv(n, 256), blk, 0, stream>>>(prob, limax_u, sumexp, n);
    head_final<<<cdiv(n, 256), blk, 0, stream>>>(prob, sumexp, res, resmask, out0, maskf, n);
    emit_x<<<cdiv((long long)n * D, 256), blk, 0, stream>>>(xbuf, xout, sout, num_res, n);
}

// Round 4
// 328.500 us; speedup vs baseline: 11.8093x; 1.1409x over previous
//
#include <hip/hip_runtime.h>

#define D 128
#define CACHE 8   // per-lane cached edges -> supports deg <= 512 (actual max ~45)

typedef __attribute__((ext_vector_type(8))) short bf16x8;
typedef __attribute__((ext_vector_type(4))) float f32x4;

__device__ __forceinline__ unsigned fenc(float f) {
    unsigned u = __float_as_uint(f);
    return (u & 0x80000000u) ? ~u : (u | 0x80000000u);
}
__device__ __forceinline__ float fdec(unsigned u) {
    return (u & 0x80000000u) ? __uint_as_float(u ^ 0x80000000u) : __uint_as_float(~u);
}
__device__ __forceinline__ unsigned short f2b(float f) {   // f32 -> bf16 (RNE)
    unsigned u = __float_as_uint(f);
    return (unsigned short)((u + 0x7fffu + ((u >> 16) & 1u)) >> 16);
}

// ---------------- input conversion f32 -> bf16 ----------------
__global__ void conv_bf16(const float* __restrict__ in, unsigned short* __restrict__ out,
                          int count8) {
    int t = blockIdx.x * blockDim.x + threadIdx.x;
    if (t >= count8) return;
    const float4* p = (const float4*)(in + (size_t)t * 8);
    float4 a = p[0], b = p[1];
    bf16x8 o;
    o[0] = (short)f2b(a.x); o[1] = (short)f2b(a.y);
    o[2] = (short)f2b(a.z); o[3] = (short)f2b(a.w);
    o[4] = (short)f2b(b.x); o[5] = (short)f2b(b.y);
    o[6] = (short)f2b(b.z); o[7] = (short)f2b(b.w);
    *(bf16x8*)(out + (size_t)t * 8) = o;
}

// pack W (f32 [K=128][N=128]) into per-(coltile,kstep,lane) B fragments, bf16
__global__ void pack_w(const float* __restrict__ W, unsigned short* __restrict__ Wp) {
    int idx = blockIdx.x * blockDim.x + threadIdx.x;
    if (idx >= 16384) return;
    int j  = idx & 7;
    int l  = (idx >> 3) & 63;
    int ks = (idx >> 9) & 3;
    int ct = idx >> 11;
    int k = ks * 32 + ((l >> 4) << 3) + j;   // B-frag: k = (lane>>4)*8 + j within kstep
    int c = ct * 16 + (l & 15);              //         col = lane & 15
    Wp[idx] = f2b(W[(size_t)k * D + c]);
}

// ---------------- MFMA GEMM: h16 = bf16(x @ W), fused as_/ad_ dots ----------------
__global__ __launch_bounds__(256) void gemm_mfma(const unsigned short* __restrict__ xb,
                                                 const unsigned short* __restrict__ Wp,
                                                 const float* __restrict__ a_src,
                                                 const float* __restrict__ a_dst,
                                                 unsigned short* __restrict__ h16,
                                                 float* __restrict__ as_, float* __restrict__ ad_,
                                                 int n) {
    __shared__ float lds[4][16][132];
    int wv = threadIdx.x >> 6;
    int lane = threadIdx.x & 63;
    int base = blockIdx.x * 64 + wv * 16;
    int arow = base + (lane & 15);
    if (arow >= n) arow = n - 1;                       // clamp; stores are guarded
    const bf16x8* aptr = (const bf16x8*)(xb + (size_t)arow * D + ((lane >> 4) << 3));
    const bf16x8* bp = (const bf16x8*)Wp;

    f32x4 acc[8];
#pragma unroll
    for (int ct = 0; ct < 8; ++ct) acc[ct] = (f32x4){0.f, 0.f, 0.f, 0.f};

#pragma unroll
    for (int ks = 0; ks < 4; ++ks) {
        bf16x8 af = aptr[ks * 4];                      // advance k by 32 elems
#pragma unroll
        for (int ct = 0; ct < 8; ++ct) {
            bf16x8 bf_ = bp[(ct * 4 + ks) * 64 + lane];
            acc[ct] = __builtin_amdgcn_mfma_f32_16x16x32_bf16(af, bf_, acc[ct], 0, 0, 0);
        }
    }

    // C/D layout: col = lane&15, row = (lane>>4)*4 + i   [guide §3, m89]
    int r0 = (lane >> 4) * 4;
    int c0 = lane & 15;
#pragma unroll
    for (int ct = 0; ct < 8; ++ct)
#pragma unroll
        for (int i = 0; i < 4; ++i)
            lds[wv][r0 + i][ct * 16 + c0] = acc[ct][i];
    __syncthreads();

    // emit h16 rows (bf16), 16B per lane per iter
#pragma unroll
    for (int i = 0; i < 4; ++i) {
        int r = (lane >> 4) + i * 4;
        int gr = base + r;
        if (gr < n) {
            const float* row = lds[wv][r];
            bf16x8 o;
#pragma unroll
            for (int j = 0; j < 8; ++j) o[j] = (short)f2b(row[c0 * 8 + j]);
            *(bf16x8*)(h16 + (size_t)gr * D + c0 * 8) = o;
        }
    }

    // fused dots: 4 lanes per row, 32 cols each
    int r = lane >> 2, q = lane & 3;
    float s1 = 0.f, s2 = 0.f;
    const float* row = lds[wv][r];
#pragma unroll
    for (int c = 0; c < 32; ++c) {
        float hv = row[q * 32 + c];
        s1 = fmaf(hv, a_src[q * 32 + c], s1);
        s2 = fmaf(hv, a_dst[q * 32 + c], s2);
    }
    s1 += __shfl_xor(s1, 1); s1 += __shfl_xor(s1, 2);
    s2 += __shfl_xor(s2, 1); s2 += __shfl_xor(s2, 2);
    int gr = base + r;
    if (q == 0 && gr < n) { as_[gr] = s1; ad_[gr] = s2; }
}

// ---------------- CSR build (graph is layer-invariant) ----------------

__global__ void deg_hist(const int* __restrict__ ad_idx, int E, int n, int* __restrict__ cnt) {
    int e = blockIdx.x * blockDim.x + threadIdx.x;
    if (e >= E + n) return;
    int dst = (e < E) ? ad_idx[E + e] : (e - E);
    atomicAdd(&cnt[dst], 1);
}

__global__ void scan1(const int* __restrict__ cnt, int* __restrict__ start,
                      int* __restrict__ bsum, int n) {
    __shared__ int lds[256];
    int t = threadIdx.x;
    int i = blockIdx.x * 256 + t;
    int v = (i < n) ? cnt[i] : 0;
    lds[t] = v;
    __syncthreads();
    for (int off = 1; off < 256; off <<= 1) {
        int o = (t >= off) ? lds[t - off] : 0;
        __syncthreads();
        lds[t] += o;
        __syncthreads();
    }
    int incl = lds[t];
    if (i < n) start[i] = incl - v;
    if (t == 255) bsum[blockIdx.x] = incl;
}

__global__ void scan2(int* __restrict__ bsum, int nb) {
    __shared__ int lds[256];
    int t = threadIdx.x;
    int v = (t < nb) ? bsum[t] : 0;
    lds[t] = v;
    __syncthreads();
    for (int off = 1; off < 256; off <<= 1) {
        int o = (t >= off) ? lds[t - off] : 0;
        __syncthreads();
        lds[t] += o;
        __syncthreads();
    }
    if (t < nb) bsum[t] = lds[t] - v;
}

__global__ void scan3(int* __restrict__ start, const int* __restrict__ bsum, int n) {
    int i = blockIdx.x * blockDim.x + threadIdx.x;
    if (i < n) start[i] += bsum[blockIdx.x];
}

__global__ void csr_scatter(const int* __restrict__ ad_idx, int E, int n,
                            const int* __restrict__ start, int* __restrict__ cursor,
                            int* __restrict__ csr_src) {
    int e = blockIdx.x * blockDim.x + threadIdx.x;
    if (e >= E + n) return;
    int src, dst;
    if (e < E) { src = ad_idx[e]; dst = ad_idx[E + e]; }
    else       { src = dst = e - E; }
    int r = atomicAdd(&cursor[dst], 1);
    csr_src[start[dst] + r] = src;
}

// ---------------- fused per-node edge softmax + gather (bf16 h) + bias + relu ----------------
__global__ void gat_aggregate(const int* __restrict__ csr_src, const int* __restrict__ start,
                              const int* __restrict__ deg, const float* __restrict__ as_,
                              const float* __restrict__ ad_, const unsigned short* __restrict__ h16,
                              const float* __restrict__ bias, float* __restrict__ out32,
                              unsigned short* __restrict__ out16, int n) {
    int wid = threadIdx.x >> 6;
    int lane = threadIdx.x & 63;
    int node = blockIdx.x * (blockDim.x >> 6) + wid;
    if (node >= n) return;
    int s0 = start[node];
    int dg = deg[node];
    float adv = ad_[node];

    float vreg[CACHE];
    int   sreg[CACHE];
    float m = -3.4e38f;
#pragma unroll
    for (int c = 0; c < CACHE; ++c) {
        int j = c * 64 + lane;
        bool ok = j < dg;
        int s = ok ? csr_src[s0 + j] : 0;
        sreg[c] = s;
        float v = -3.4e38f;
        if (ok) {
            v = as_[s] + adv;
            v = v >= 0.f ? v : 0.2f * v;
        }
        vreg[c] = v;
        m = fmaxf(m, v);
    }
    for (int off = 32; off; off >>= 1) m = fmaxf(m, __shfl_xor(m, off));

    float dsum = 0.f;
#pragma unroll
    for (int c = 0; c < CACHE; ++c) {
        int j = c * 64 + lane;
        float e = (j < dg) ? __expf(vreg[c] - m) : 0.f;
        vreg[c] = e;
        dsum += e;
    }
    for (int off = 32; off; off >>= 1) dsum += __shfl_xor(dsum, off);
    float inv = 1.f / (dsum + 1e-16f);

    float acc0 = 0.f, acc1 = 0.f;
#pragma unroll
    for (int c = 0; c < CACHE; ++c) {
        if (c * 64 < dg) {
            int mc = min(64, dg - c * 64);
            for (int l = 0; l < mc; ++l) {
                float a   = __shfl(vreg[c], l) * inv;
                int  srcj = __shfl(sreg[c], l);
                unsigned hv = *(const unsigned*)(h16 + (size_t)srcj * D + lane * 2);
                acc0 = fmaf(a, __uint_as_float(hv << 16), acc0);
                acc1 = fmaf(a, __uint_as_float(hv & 0xffff0000u), acc1);
            }
        }
    }
    float2 bv = *(const float2*)(bias + lane * 2);
    float o0 = acc0 + bv.x, o1 = acc1 + bv.y;
    o0 = o0 > 0.f ? o0 : 0.f;
    o1 = o1 > 0.f ? o1 : 0.f;
    if (out32) *(float2*)(out32 + (size_t)node * D + lane * 2) = make_float2(o0, o1);
    if (out16) {
        ushort2 u2;
        u2.x = f2b(o0);
        u2.y = f2b(o1);
        *(ushort2*)(out16 + (size_t)node * D + lane * 2) = u2;
    }
}

// ---------------- head ----------------

__global__ void head_li(const float* __restrict__ x, const float* __restrict__ w_lin,
                        const float* __restrict__ b_lin, const int* __restrict__ resmask,
                        float* __restrict__ pr, unsigned* __restrict__ limax_u, int n) {
    int i = blockIdx.x * blockDim.x + threadIdx.x;
    unsigned enc = 0u;
    if (i < n) {
        const float* xr = x + (size_t)i * D;
        float s = 0.f;
#pragma unroll
        for (int d = 0; d < D; d += 4) {
            float4 xv = *(const float4*)(xr + d);
            float4 wv = *(const float4*)(w_lin + d);
            s = fmaf(xv.x, wv.x, s);
            s = fmaf(xv.y, wv.y, s);
            s = fmaf(xv.z, wv.z, s);
            s = fmaf(xv.w, wv.w, s);
        }
        s += b_lin[0];
        if (resmask[i] == 0) s = -1000000000.0f;
        pr[i] = s;
        enc = fenc(s);
    }
    unsigned t = enc;
    for (int off = 32; off; off >>= 1) {
        unsigned o = __shfl_down(t, off);
        t = t > o ? t : o;
    }
    if ((threadIdx.x & 63) == 0) atomicMax(limax_u, t);
}

__global__ void head_exp(float* __restrict__ pr, const unsigned* __restrict__ limax_u,
                         float* __restrict__ sumexp, int n) {
    int i = blockIdx.x * blockDim.x + threadIdx.x;
    float m = fdec(*limax_u);
    float u = 0.f;
    if (i < n) {
        u = expf(pr[i] - m);
        pr[i] = u;
    }
    float t = u;
    for (int off = 32; off; off >>= 1) t += __shfl_down(t, off);
    if ((threadIdx.x & 63) == 0) atomicAdd(sumexp, t);
}

__global__ void head_final(float* __restrict__ pr, const float* __restrict__ sumexp,
                           const float* __restrict__ res, const int* __restrict__ resmask,
                           float* __restrict__ loss_out, float* __restrict__ maskf, int n) {
    int i = blockIdx.x * blockDim.x + threadIdx.x;
    float lt = 0.f;
    if (i < n) {
        float p = pr[i] / (*sumexp);
        pr[i] = p;
        float pc = fminf(fmaxf(p, 1e-10f), 1.0f);
        lt = -logf(pc) * res[i];
        maskf[i] = (float)resmask[i];
    }
    float t = lt;
    for (int off = 32; off; off >>= 1) t += __shfl_down(t, off);
    if ((threadIdx.x & 63) == 0) atomicAdd(loss_out, t);
}

__global__ void emit_x(const float* __restrict__ x2, float* __restrict__ xout,
                       float* __restrict__ sout, const int* __restrict__ num_res, int n) {
    int t = blockIdx.x * blockDim.x + threadIdx.x;
    if (t >= n * D) return;
    float v = x2[t];
    xout[t] = v;
    int row = t >> 7;
    if (row < num_res[0]) sout[t] = v;
}

extern "C" void kernel_launch(void* const* d_in, const int* in_sizes, int n_in,
                              void* d_out, int out_size, void* d_ws, size_t ws_size,
                              hipStream_t stream) {
    const float* input_node = (const float*)d_in[0];
    const int*   inputad    = (const int*)d_in[1];
    const float* res        = (const float*)d_in[2];
    const int*   resmask    = (const int*)d_in[3];
    const int*   num_res    = (const int*)d_in[4];
    const float* W1     = (const float*)d_in[5];
    const float* a_src1 = (const float*)d_in[6];
    const float* a_dst1 = (const float*)d_in[7];
    const float* b1     = (const float*)d_in[8];
    const float* W2     = (const float*)d_in[9];
    const float* a_src2 = (const float*)d_in[10];
    const float* a_dst2 = (const float*)d_in[11];
    const float* b2     = (const float*)d_in[12];
    const float* w_lin  = (const float*)d_in[13];
    const float* b_lin  = (const float*)d_in[14];

    int n = in_sizes[0] / D;
    int E = in_sizes[1] / 2;
    int Et = E + n;

    // workspace carve (16B aligned pieces)
    char* w = (char*)d_ws;
    unsigned short* xb16 = (unsigned short*)w; w += (size_t)n * D * 2;  // gemm input (both layers)
    unsigned short* h16  = (unsigned short*)w; w += (size_t)n * D * 2;
    float* xbuf  = (float*)w; w += (size_t)n * D * 4;                   // layer-2 f32 out
    unsigned short* Wp1 = (unsigned short*)w; w += 16384 * 2;
    unsigned short* Wp2 = (unsigned short*)w; w += 16384 * 2;
    float* as_   = (float*)w; w += (size_t)n * 4;
    float* ad_   = (float*)w; w += (size_t)n * 4;
    int*   deg   = (int*)w;   w += (size_t)n * 4;
    int*   startv= (int*)w;   w += (size_t)n * 4;
    int*   cursor= (int*)w;   w += (size_t)n * 4;
    int*   csr_src=(int*)w;   w += (size_t)Et * 4;
    int*   bsum  = (int*)w;   w += 1024;
    unsigned* limax_u = (unsigned*)w; w += 16;
    float* sumexp = (float*)w; w += 16;

    // d_out carve
    float* out0  = (float*)d_out;            // loss (1)
    float* prob  = out0 + 1;                 // N
    float* xout  = prob + n;                 // N*D
    float* maskf = xout + (size_t)n * D;     // N
    float* sout  = maskf + n;                // K*D

    dim3 blk(256);
    auto cdiv = [](long long a, long long b) { return (unsigned)((a + b - 1) / b); };
    unsigned nb = cdiv(n, 256);

    // ---- conversions / packing ----
    conv_bf16<<<cdiv((long long)n * D / 8, 256), blk, 0, stream>>>(input_node, xb16, n * D / 8);
    pack_w<<<64, blk, 0, stream>>>(W1, Wp1);
    pack_w<<<64, blk, 0, stream>>>(W2, Wp2);

    // ---- CSR build (once; graph shared by both layers) ----
    hipMemsetAsync(deg, 0, (size_t)n * 4, stream);
    deg_hist<<<cdiv(Et, 256), blk, 0, stream>>>(inputad, E, n, deg);
    scan1<<<nb, blk, 0, stream>>>(deg, startv, bsum, n);
    scan2<<<1, blk, 0, stream>>>(bsum, (int)nb);
    scan3<<<nb, blk, 0, stream>>>(startv, bsum, n);
    hipMemsetAsync(cursor, 0, (size_t)n * 4, stream);
    csr_scatter<<<cdiv(Et, 256), blk, 0, stream>>>(inputad, E, n, startv, cursor, csr_src);

    unsigned agg_grid = cdiv(n, 4);    // 4 waves/block, 1 node/wave
    unsigned gemm_grid = cdiv(n, 64);  // 4 waves/block, 16 rows/wave

    // ---- Layer 1 ----
    gemm_mfma<<<gemm_grid, blk, 0, stream>>>(xb16, Wp1, a_src1, a_dst1, h16, as_, ad_, n);
    gat_aggregate<<<agg_grid, blk, 0, stream>>>(csr_src, startv, deg, as_, ad_, h16, b1,
                                                nullptr, xb16, n);   // bf16 out -> gemm2 input

    // ---- Layer 2 ----
    gemm_mfma<<<gemm_grid, blk, 0, stream>>>(xb16, Wp2, a_src2, a_dst2, h16, as_, ad_, n);
    gat_aggregate<<<agg_grid, blk, 0, stream>>>(csr_src, startv, deg, as_, ad_, h16, b2,
                                                xbuf, nullptr, n);   // f32 out -> head/emit

    // ---- Head ----
    hipMemsetAsync(limax_u, 0, 4, stream);
    hipMemsetAsync(sumexp, 0, 4, stream);
    hipMemsetAsync(out0, 0, 4, stream);
    head_li<<<cdiv(n, 256), blk, 0, stream>>>(xbuf, w_lin, b_lin, resmask, prob, limax_u, n);
    head_exp<<<cdiv(n, 256), blk, 0, stream>>>(prob, limax_u, sumexp, n);
    head_final<<<cdiv(n, 256), blk, 0, stream>>>(prob, sumexp, res, resmask, out0, maskf, n);
    emit_x<<<cdiv((long long)n * D, 256), blk, 0, stream>>>(xbuf, xout, sout, num_res, n);
}